// Round 1
// baseline (457.497 us; speedup 1.0000x reference)
//
#include <hip/hip_runtime.h>
#include <stdint.h>

typedef __attribute__((ext_vector_type(8))) short short8;
typedef __attribute__((ext_vector_type(4))) float f32x4;

__device__ __forceinline__ float bf2f(short s) {
    union { unsigned u; float f; } c;
    c.u = ((unsigned)(unsigned short)s) << 16;
    return c.f;
}
__device__ __forceinline__ short f2bf(float f) {
    union { float f; unsigned u; } c; c.f = f;
    unsigned u = c.u + 0x7fffu + ((c.u >> 16) & 1u);
    return (short)(u >> 16);
}

// ---------------------------------------------------------------- weights cvt
// layout (shorts): wq@0 wk@1M wv@2M wo@3M | sum_fc1@4M sum_fc2@8M reg_fc1@12M reg_fc2@16M
__global__ __launch_bounds__(256) void cvt_w(
    const float* __restrict__ wq, const float* __restrict__ wk,
    const float* __restrict__ wv, const float* __restrict__ wo,
    const float* __restrict__ f1s, const float* __restrict__ f2s,
    const float* __restrict__ f1r, const float* __restrict__ f2r,
    short* __restrict__ dst)
{
    size_t i = ((size_t)blockIdx.x * 256 + threadIdx.x) * 4;
    const float* src; size_t off;
    if (i < 4194304) {
        int seg = (int)(i >> 20);
        src = seg == 0 ? wq : seg == 1 ? wk : seg == 2 ? wv : wo;
        off = i & 1048575;
    } else {
        size_t ii = i - 4194304;
        int seg = (int)(ii >> 22);
        src = seg == 0 ? f1s : seg == 1 ? f2s : seg == 2 ? f1r : f2r;
        off = ii & 4194303;
    }
    float4 v = *(const float4*)(src + off);
    short4 o;
    o.x = f2bf(v.x); o.y = f2bf(v.y); o.z = f2bf(v.z); o.w = f2bf(v.w);
    *(short4*)(dst + i) = o;
}

// ---------------------------------------------------------------- layernorm
// PHASE 0: out_all[row] = LN(x[row]) (attn pre-LN)
// PHASE 1: scatter to out_s [B*16][1024], out_r [B*2048][1024] (FFN pre-LN)
template<int PHASE>
__global__ __launch_bounds__(256) void ln_k(
    const float* __restrict__ xin,
    const float* __restrict__ g_sum, const float* __restrict__ b_sum,
    const float* __restrict__ g_reg, const float* __restrict__ b_reg,
    short* __restrict__ out_all, short* __restrict__ out_s, short* __restrict__ out_r)
{
    int row = blockIdx.x;
    int b = row / 2064, t = row - b * 2064;
    int tid = threadIdx.x;
    const float* xr = xin + (size_t)row * 1024;
    float4 v = *(const float4*)(xr + tid * 4);
    float s = v.x + v.y + v.z + v.w;
#pragma unroll
    for (int off = 1; off < 64; off <<= 1) s += __shfl_xor(s, off);
    __shared__ float red[8];
    if ((tid & 63) == 0) red[tid >> 6] = s;
    __syncthreads();
    float mu = (red[0] + red[1] + red[2] + red[3]) * (1.0f / 1024.0f);
    float a0 = v.x - mu, a1 = v.y - mu, a2 = v.z - mu, a3 = v.w - mu;
    float qq = a0 * a0 + a1 * a1 + a2 * a2 + a3 * a3;
#pragma unroll
    for (int off = 1; off < 64; off <<= 1) qq += __shfl_xor(qq, off);
    if ((tid & 63) == 0) red[4 + (tid >> 6)] = qq;
    __syncthreads();
    float var = (red[4] + red[5] + red[6] + red[7]) * (1.0f / 1024.0f);
    float rs = rsqrtf(var + 1e-5f);
    const float* g  = (t < 16) ? g_sum : g_reg;
    const float* be = (t < 16) ? b_sum : b_reg;
    int c = tid * 4;
    short4 o;
    o.x = f2bf(a0 * rs * g[c]     + be[c]);
    o.y = f2bf(a1 * rs * g[c + 1] + be[c + 1]);
    o.z = f2bf(a2 * rs * g[c + 2] + be[c + 2]);
    o.w = f2bf(a3 * rs * g[c + 3] + be[c + 3]);
    short* dst;
    if (PHASE == 0) dst = out_all + (size_t)row * 1024;
    else dst = (t < 16) ? (out_s + ((size_t)b * 16 + t) * 1024)
                        : (out_r + ((size_t)b * 2048 + (t - 16)) * 1024);
    *(short4*)(dst + c) = o;
}

// ---------------------------------------------------------------- GEMM C = A * B^T
// A [M][K] bf16 row-major, B [N][K] bf16 row-major (weights). 128x128 tile, BK=32,
// 4 waves (2x2 of 64x64), 4x4 16x16x32 frags per wave.
// MODE 0: QKV — B/out selected by blockIdx.y>>3, out bf16 ld 1024
// MODE 1: WO  — out fp32 = resid + acc, ld 1024
// MODE 2: FFN1 — out bf16 = relu(acc + bias), ld 4096
// MODE 3: FFN2 — out fp32 at mapped row = resid[g] + acc + bias, ld 1024
template<int MODE>
__global__ __launch_bounds__(256) void gemm_bt(
    const short* __restrict__ A, int M, int K,
    const short* __restrict__ B0, const short* __restrict__ B1, const short* __restrict__ B2,
    const float* __restrict__ bias, const float* __restrict__ resid,
    void* __restrict__ o0, void* __restrict__ o1, void* __restrict__ o2, int seg)
{
    const int tid = threadIdx.x;
    const int w = tid >> 6, l = tid & 63;
    const int lr = l & 15, lh = l >> 4;
    const int m0 = blockIdx.x * 128;
    int ntile = blockIdx.y, nsel = 0;
    const short* B = B0;
    if (MODE == 0) { nsel = ntile >> 3; ntile &= 7; B = nsel == 0 ? B0 : (nsel == 1 ? B1 : B2); }
    const int n0 = ntile * 128;
    const int wr = (w >> 1) * 64, wc = (w & 1) * 64;

    __shared__ __align__(16) short As[128 * 40];   // pad 32->40: 2-way (free) banks
    __shared__ __align__(16) short Bs[128 * 40];

    f32x4 acc[4][4];
#pragma unroll
    for (int m = 0; m < 4; ++m)
#pragma unroll
        for (int n = 0; n < 4; ++n) acc[m][n] = (f32x4){0.f, 0.f, 0.f, 0.f};

    for (int k0 = 0; k0 < K; k0 += 32) {
#pragma unroll
        for (int i = 0; i < 2; ++i) {
            int ch = tid + 256 * i;          // 512 chunks of 8 elems (16B)
            int row = ch >> 2, kk = (ch & 3) << 3;
            int ar = m0 + row; if (ar > M - 1) ar = M - 1;   // clamp (garbage rows unused)
            *(int4*)(As + row * 40 + kk) = *(const int4*)(A + (size_t)ar * K + k0 + kk);
            *(int4*)(Bs + row * 40 + kk) = *(const int4*)(B + (size_t)(n0 + row) * K + k0 + kk);
        }
        __syncthreads();
        short8 af[4], bfr[4];
#pragma unroll
        for (int m = 0; m < 4; ++m)
            af[m] = *(const short8*)(As + (wr + m * 16 + lr) * 40 + lh * 8);
#pragma unroll
        for (int n = 0; n < 4; ++n)
            bfr[n] = *(const short8*)(Bs + (wc + n * 16 + lr) * 40 + lh * 8);
#pragma unroll
        for (int m = 0; m < 4; ++m)
#pragma unroll
            for (int n = 0; n < 4; ++n)
                acc[m][n] = __builtin_amdgcn_mfma_f32_16x16x32_bf16(af[m], bfr[n], acc[m][n], 0, 0, 0);
        __syncthreads();
    }

#pragma unroll
    for (int m = 0; m < 4; ++m) {
#pragma unroll
        for (int n = 0; n < 4; ++n) {
            int gc = n0 + wc + n * 16 + lr;
#pragma unroll
            for (int j = 0; j < 4; ++j) {
                int gr = m0 + wr + m * 16 + lh * 4 + j;
                if (gr >= M) continue;
                float val = acc[m][n][j];
                if (MODE == 0) {
                    short* o = (short*)(nsel == 0 ? o0 : (nsel == 1 ? o1 : o2));
                    o[(size_t)gr * 1024 + gc] = f2bf(val);
                } else if (MODE == 1) {
                    ((float*)o0)[(size_t)gr * 1024 + gc] = resid[(size_t)gr * 1024 + gc] + val;
                } else if (MODE == 2) {
                    val += bias[gc];
                    val = val > 0.f ? val : 0.f;
                    ((short*)o0)[(size_t)gr * 4096 + gc] = f2bf(val);
                } else {
                    int g = (seg == 0) ? ((gr >> 4) * 2064 + (gr & 15))
                                       : ((gr >> 11) * 2064 + 16 + (gr & 2047));
                    ((float*)o0)[(size_t)g * 1024 + gc] =
                        resid[(size_t)g * 1024 + gc] + val + bias[gc];
                }
            }
        }
    }
}

// ---------------------------------------------------------------- chunk attention (reg queries)
// one block per (chunk c, head h, batch b): 128 queries x (16 sum + 128 reg) keys.
// scores via mfma(Q, K-frag); full-row softmax in regs (16-lane shfl groups);
// P -> LDS (bf16, keys padded to 160 with zeros); PV via mfma(P, Vt-frag).
__global__ __launch_bounds__(256) void attn_reg(
    const short* __restrict__ q, const short* __restrict__ k,
    const short* __restrict__ v, short* __restrict__ ctx)
{
    __shared__ __align__(16) short Pl[128 * 168];  // P[128][160+pad8]; first aliased K[144][72]
    __shared__ __align__(16) short Vt[64 * 168];   // V^T [64][160+pad8]
    short* Kl = Pl;

    const int tid = threadIdx.x;
    const int w = tid >> 6, l = tid & 63, lr = l & 15, lh = l >> 4;
    const int c = blockIdx.x, h = blockIdx.y, b = blockIdx.z;
    const int hc = h * 64;
    const size_t rowq0 = (size_t)b * 2064 + 16 + (size_t)c * 128;

    // stage K rows [144][72]: keys 0..15 = sum tokens, 16..143 = this chunk
    for (int ch = tid; ch < 1152; ch += 256) {
        int row = ch >> 3, kk = (ch & 7) << 3;
        size_t grow = (row < 16) ? ((size_t)b * 2064 + row) : (rowq0 + row - 16);
        *(int4*)(Kl + row * 72 + kk) = *(const int4*)(k + grow * 1024 + hc + kk);
    }
    // stage V transposed: Vt[d][j] = V[j][d]
    for (int ch = tid; ch < 1152; ch += 256) {
        int j = ch % 144, db = ch / 144;
        size_t grow = (j < 16) ? ((size_t)b * 2064 + j) : (rowq0 + j - 16);
        short8 dv = *(const short8*)(v + grow * 1024 + hc + db * 8);
#pragma unroll
        for (int i = 0; i < 8; ++i) Vt[(db * 8 + i) * 168 + j] = dv[i];
    }
    // zero Vt pad cols 144..159
    for (int idx = tid; idx < 1024; idx += 256) {
        int d = idx >> 4, jj = 144 + (idx & 15);
        Vt[d * 168 + jj] = 0;
    }
    __syncthreads();

    // Q fragments straight from global (wave w owns query rows w*32 .. w*32+31)
    short8 qf[2][2];
#pragma unroll
    for (int m = 0; m < 2; ++m) {
        size_t grow = rowq0 + w * 32 + m * 16 + lr;
#pragma unroll
        for (int ks = 0; ks < 2; ++ks)
            qf[m][ks] = *(const short8*)(q + grow * 1024 + hc + ks * 32 + lh * 8);
    }

    // scores S = Q K^T
    f32x4 s[2][9];
#pragma unroll
    for (int m = 0; m < 2; ++m)
#pragma unroll
        for (int n = 0; n < 9; ++n) s[m][n] = (f32x4){0.f, 0.f, 0.f, 0.f};
#pragma unroll
    for (int n = 0; n < 9; ++n) {
        const short* kr = Kl + (n * 16 + lr) * 72;
        short8 k0 = *(const short8*)(kr + lh * 8);
        short8 k1 = *(const short8*)(kr + 32 + lh * 8);
        s[0][n] = __builtin_amdgcn_mfma_f32_16x16x32_bf16(qf[0][0], k0, s[0][n], 0, 0, 0);
        s[0][n] = __builtin_amdgcn_mfma_f32_16x16x32_bf16(qf[0][1], k1, s[0][n], 0, 0, 0);
        s[1][n] = __builtin_amdgcn_mfma_f32_16x16x32_bf16(qf[1][0], k0, s[1][n], 0, 0, 0);
        s[1][n] = __builtin_amdgcn_mfma_f32_16x16x32_bf16(qf[1][1], k1, s[1][n], 0, 0, 0);
    }

    // mask + softmax (unnormalized P kept in s; 1/l applied at C-write)
    float inv_[2][4];
#pragma unroll
    for (int m = 0; m < 2; ++m) {
#pragma unroll
        for (int j = 0; j < 4; ++j) {
            int p = w * 32 + m * 16 + lh * 4 + j;
            float best = -1e30f;
            float e[9];
#pragma unroll
            for (int n = 0; n < 9; ++n) {
                int kk = n * 16 + lr;
                bool vis = (kk < 16) ? (kk < c) : (kk - 16 <= p);
                float val = vis ? s[m][n][j] * 0.125f : -1e30f;
                e[n] = val;
                best = fmaxf(best, val);
            }
#pragma unroll
            for (int off = 1; off < 16; off <<= 1) best = fmaxf(best, __shfl_xor(best, off));
            float sm = 0.f;
#pragma unroll
            for (int n = 0; n < 9; ++n) {
                float ex = __expf(e[n] - best);
                s[m][n][j] = ex;
                sm += ex;
            }
#pragma unroll
            for (int off = 1; off < 16; off <<= 1) sm += __shfl_xor(sm, off);
            inv_[m][j] = 1.0f / sm;
        }
    }

    __syncthreads();   // everyone done reading Kl before P overwrites it
#pragma unroll
    for (int m = 0; m < 2; ++m)
#pragma unroll
        for (int n = 0; n < 9; ++n)
#pragma unroll
            for (int j = 0; j < 4; ++j)
                Pl[(w * 32 + m * 16 + lh * 4 + j) * 168 + n * 16 + lr] = f2bf(s[m][n][j]);
    // zero P pad cols 144..159 (wave-local rows)
    for (int idx = l; idx < 512; idx += 64) {
        int rr = idx >> 4, kkp = 144 + (idx & 15);
        Pl[(w * 32 + rr) * 168 + kkp] = 0;
    }
    __syncthreads();

    // ctx = P V  (K=160 -> 5 k-steps)
    f32x4 dacc[2][4];
#pragma unroll
    for (int m = 0; m < 2; ++m)
#pragma unroll
        for (int n = 0; n < 4; ++n) dacc[m][n] = (f32x4){0.f, 0.f, 0.f, 0.f};
#pragma unroll
    for (int ks = 0; ks < 5; ++ks) {
        int kk0 = ks * 32;
        short8 pa[2];
#pragma unroll
        for (int m = 0; m < 2; ++m)
            pa[m] = *(const short8*)(Pl + (w * 32 + m * 16 + lr) * 168 + kk0 + lh * 8);
#pragma unroll
        for (int n = 0; n < 4; ++n) {
            short8 vb = *(const short8*)(Vt + (n * 16 + lr) * 168 + kk0 + lh * 8);
            dacc[0][n] = __builtin_amdgcn_mfma_f32_16x16x32_bf16(pa[0], vb, dacc[0][n], 0, 0, 0);
            dacc[1][n] = __builtin_amdgcn_mfma_f32_16x16x32_bf16(pa[1], vb, dacc[1][n], 0, 0, 0);
        }
    }

#pragma unroll
    for (int m = 0; m < 2; ++m)
#pragma unroll
        for (int n = 0; n < 4; ++n)
#pragma unroll
            for (int j = 0; j < 4; ++j) {
                int p = w * 32 + m * 16 + lh * 4 + j;
                ctx[(rowq0 + p) * 1024 + hc + n * 16 + lr] = f2bf(dacc[m][n][j] * inv_[m][j]);
            }
}

// ---------------------------------------------------------------- sum-token attention
// one wave per (b,h,s): query = sum token s; keys = sum tokens 0..s + reg chunk s (128)
__global__ __launch_bounds__(64) void attn_sum(
    const short* __restrict__ q, const short* __restrict__ k,
    const short* __restrict__ v, short* __restrict__ ctx)
{
    int idx = blockIdx.x;
    int b = idx >> 8, h = (idx >> 4) & 15, s = idx & 15;
    int l = threadIdx.x;
    int hc = h * 64;
    size_t qrow = (size_t)b * 2064 + s;
    __shared__ float qv[64];
    __shared__ float pp[192];
    qv[l] = bf2f(q[qrow * 1024 + hc + l]);
    __syncthreads();
    float sc[3];
#pragma unroll
    for (int i = 0; i < 3; ++i) {
        int j = l + i * 64;
        float t = -1e30f;
        if (j < 144 && (j >= 16 || j <= s)) {
            size_t kr = (j < 16) ? ((size_t)b * 2064 + j)
                                 : ((size_t)b * 2064 + 16 + (size_t)s * 128 + (j - 16));
            const short* kp = k + kr * 1024 + hc;
            float acc = 0.f;
            for (int d = 0; d < 64; ++d) acc += qv[d] * bf2f(kp[d]);
            t = acc * 0.125f;
        }
        sc[i] = t;
    }
    float mx = fmaxf(sc[0], fmaxf(sc[1], sc[2]));
#pragma unroll
    for (int off = 1; off < 64; off <<= 1) mx = fmaxf(mx, __shfl_xor(mx, off));
    float sm = 0.f;
#pragma unroll
    for (int i = 0; i < 3; ++i) {
        float ex = (sc[i] > -1e29f) ? __expf(sc[i] - mx) : 0.f;
        pp[l + i * 64] = ex;
        sm += ex;
    }
#pragma unroll
    for (int off = 1; off < 64; off <<= 1) sm += __shfl_xor(sm, off);
    __syncthreads();
    float invs = 1.0f / sm;
    float acc = 0.f;
    for (int j = 0; j < 144; ++j) {
        float pj = pp[j];
        size_t vr = (j < 16) ? ((size_t)b * 2064 + j)
                             : ((size_t)b * 2064 + 16 + (size_t)s * 128 + (j - 16));
        acc += pj * bf2f(v[vr * 1024 + hc + l]);
    }
    ctx[qrow * 1024 + hc + l] = f2bf(acc * invs);
}

// ---------------------------------------------------------------- launch
extern "C" void kernel_launch(void* const* d_in, const int* in_sizes, int n_in,
                              void* d_out, int out_size, void* d_ws, size_t ws_size,
                              hipStream_t stream) {
    const float* x    = (const float*)d_in[0];
    const float* wq   = (const float*)d_in[1];
    const float* wk   = (const float*)d_in[2];
    const float* wv   = (const float*)d_in[3];
    const float* wo   = (const float*)d_in[4];
    const float* lsg  = (const float*)d_in[5];
    const float* lsb  = (const float*)d_in[6];
    const float* lrg  = (const float*)d_in[7];
    const float* lrb  = (const float*)d_in[8];
    const float* sf1w = (const float*)d_in[9];
    const float* sf1b = (const float*)d_in[10];
    const float* sf2w = (const float*)d_in[11];
    const float* sf2b = (const float*)d_in[12];
    const float* rf1w = (const float*)d_in[13];
    const float* rf1b = (const float*)d_in[14];
    const float* rf2w = (const float*)d_in[15];
    const float* rf2b = (const float*)d_in[16];
    const float* fsg  = (const float*)d_in[17];
    const float* fsb  = (const float*)d_in[18];
    const float* frg  = (const float*)d_in[19];
    const float* frb  = (const float*)d_in[20];
    float* out = (float*)d_out;

    char* ws = (char*)d_ws;
    // bf16 weights: 20M shorts = 40 MB
    short* wbf   = (short*)ws;
    short* wq_b  = wbf;
    short* wk_b  = wbf + 1048576;
    short* wv_b  = wbf + 2097152;
    short* wo_b  = wbf + 3145728;
    short* f1s_b = wbf + 4194304;
    short* f2s_b = wbf + 8388608;
    short* f1r_b = wbf + 12582912;
    short* f2r_b = wbf + 16777216;
    // region 1: h_all (phase A) == h2_reg + h2_sum (phase B)
    short* h_all  = (short*)(ws + 41943040);
    short* h2_reg = h_all;
    short* h2_sum = (short*)(ws + 41943040 + 8388608);
    // region 2: q,k,v,ctx (phase A) == f1_reg + f1_sum (phase B)
    short* qb   = (short*)(ws + 50397184);
    short* kb   = qb + 4227072;
    short* vb   = kb + 4227072;
    short* ctxb = vb + 4227072;
    short* f1_reg = qb;
    short* f1_sum = qb + 16777216;
    // x1 (fp32, post-attention residual)
    float* x1 = (float*)(ws + 84213760);

    // 1. weights -> bf16
    cvt_w<<<20480, 256, 0, stream>>>(wq, wk, wv, wo, sf1w, sf2w, rf1w, rf2w, wbf);
    // 2. pre-attn LN
    ln_k<0><<<4128, 256, 0, stream>>>(x, lsg, lsb, lrg, lrb, h_all, nullptr, nullptr);
    // 3. fused QKV
    gemm_bt<0><<<dim3(33, 24), 256, 0, stream>>>(h_all, 4128, 1024, wq_b, wk_b, wv_b,
                                                 nullptr, nullptr, qb, kb, vb, 0);
    // 4. attention
    attn_reg<<<dim3(16, 16, 2), 256, 0, stream>>>(qb, kb, vb, ctxb);
    attn_sum<<<512, 64, 0, stream>>>(qb, kb, vb, ctxb);
    // 5. W_O + residual -> x1 (fp32)
    gemm_bt<1><<<dim3(33, 8), 256, 0, stream>>>(ctxb, 4128, 1024, wo_b, nullptr, nullptr,
                                                nullptr, x, x1, nullptr, nullptr, 0);
    // 6. pre-FFN LN (scatter to compact sum/reg)
    ln_k<1><<<4128, 256, 0, stream>>>(x1, fsg, fsb, frg, frb, nullptr, h2_sum, h2_reg);
    // 7. FFN1 (bias + relu)
    gemm_bt<2><<<dim3(32, 32), 256, 0, stream>>>(h2_reg, 4096, 1024, f1r_b, nullptr, nullptr,
                                                 rf1b, nullptr, f1_reg, nullptr, nullptr, 0);
    gemm_bt<2><<<dim3(1, 32), 256, 0, stream>>>(h2_sum, 32, 1024, f1s_b, nullptr, nullptr,
                                                sf1b, nullptr, f1_sum, nullptr, nullptr, 0);
    // 8. FFN2 (bias + residual, scatter) -> d_out
    gemm_bt<3><<<dim3(32, 8), 256, 0, stream>>>(f1_reg, 4096, 4096, f2r_b, nullptr, nullptr,
                                                rf2b, x1, out, nullptr, nullptr, 1);
    gemm_bt<3><<<dim3(1, 8), 256, 0, stream>>>(f1_sum, 32, 4096, f2s_b, nullptr, nullptr,
                                               sf2b, x1, out, nullptr, nullptr, 0);
}

// Round 2
// 331.807 us; speedup vs baseline: 1.3788x; 1.3788x over previous
//
#include <hip/hip_runtime.h>
#include <stdint.h>

typedef __attribute__((ext_vector_type(8))) short short8;
typedef __attribute__((ext_vector_type(4))) float f32x4;

__device__ __forceinline__ float bf2f(short s) {
    union { unsigned u; float f; } c;
    c.u = ((unsigned)(unsigned short)s) << 16;
    return c.f;
}
__device__ __forceinline__ short f2bf(float f) {
    union { float f; unsigned u; } c; c.f = f;
    unsigned u = c.u + 0x7fffu + ((c.u >> 16) & 1u);
    return (short)(u >> 16);
}
// async global->LDS, 16B per lane; lds dst must be wave-uniform base (HW adds lane*16)
__device__ __forceinline__ void gll16(const short* g, short* l) {
    __builtin_amdgcn_global_load_lds(
        (const __attribute__((address_space(1))) unsigned int*)g,
        (__attribute__((address_space(3))) unsigned int*)l, 16, 0, 0);
}

// ---------------------------------------------------------------- weights cvt
// layout (shorts): wq@0 wk@1M wv@2M wo@3M | sum_fc1@4M sum_fc2@8M reg_fc1@12M reg_fc2@16M
__global__ __launch_bounds__(256) void cvt_w(
    const float* __restrict__ wq, const float* __restrict__ wk,
    const float* __restrict__ wv, const float* __restrict__ wo,
    const float* __restrict__ f1s, const float* __restrict__ f2s,
    const float* __restrict__ f1r, const float* __restrict__ f2r,
    short* __restrict__ dst)
{
    size_t i = ((size_t)blockIdx.x * 256 + threadIdx.x) * 4;
    const float* src; size_t off;
    if (i < 4194304) {
        int seg = (int)(i >> 20);
        src = seg == 0 ? wq : seg == 1 ? wk : seg == 2 ? wv : wo;
        off = i & 1048575;
    } else {
        size_t ii = i - 4194304;
        int seg = (int)(ii >> 22);
        src = seg == 0 ? f1s : seg == 1 ? f2s : seg == 2 ? f1r : f2r;
        off = ii & 4194303;
    }
    float4 v = *(const float4*)(src + off);
    short4 o;
    o.x = f2bf(v.x); o.y = f2bf(v.y); o.z = f2bf(v.z); o.w = f2bf(v.w);
    *(short4*)(dst + i) = o;
}

// ---------------------------------------------------------------- layernorm
template<int PHASE>
__global__ __launch_bounds__(256) void ln_k(
    const float* __restrict__ xin,
    const float* __restrict__ g_sum, const float* __restrict__ b_sum,
    const float* __restrict__ g_reg, const float* __restrict__ b_reg,
    short* __restrict__ out_all, short* __restrict__ out_s, short* __restrict__ out_r)
{
    int row = blockIdx.x;
    int b = row / 2064, t = row - b * 2064;
    int tid = threadIdx.x;
    const float* xr = xin + (size_t)row * 1024;
    float4 v = *(const float4*)(xr + tid * 4);
    float s = v.x + v.y + v.z + v.w;
#pragma unroll
    for (int off = 1; off < 64; off <<= 1) s += __shfl_xor(s, off);
    __shared__ float red[8];
    if ((tid & 63) == 0) red[tid >> 6] = s;
    __syncthreads();
    float mu = (red[0] + red[1] + red[2] + red[3]) * (1.0f / 1024.0f);
    float a0 = v.x - mu, a1 = v.y - mu, a2 = v.z - mu, a3 = v.w - mu;
    float qq = a0 * a0 + a1 * a1 + a2 * a2 + a3 * a3;
#pragma unroll
    for (int off = 1; off < 64; off <<= 1) qq += __shfl_xor(qq, off);
    if ((tid & 63) == 0) red[4 + (tid >> 6)] = qq;
    __syncthreads();
    float var = (red[4] + red[5] + red[6] + red[7]) * (1.0f / 1024.0f);
    float rs = rsqrtf(var + 1e-5f);
    const float* g  = (t < 16) ? g_sum : g_reg;
    const float* be = (t < 16) ? b_sum : b_reg;
    int c = tid * 4;
    short4 o;
    o.x = f2bf(a0 * rs * g[c]     + be[c]);
    o.y = f2bf(a1 * rs * g[c + 1] + be[c + 1]);
    o.z = f2bf(a2 * rs * g[c + 2] + be[c + 2]);
    o.w = f2bf(a3 * rs * g[c + 3] + be[c + 3]);
    short* dst;
    if (PHASE == 0) dst = out_all + (size_t)row * 1024;
    else dst = (t < 16) ? (out_s + ((size_t)b * 16 + t) * 1024)
                        : (out_r + ((size_t)b * 2048 + (t - 16)) * 1024);
    *(short4*)(dst + c) = o;
}

// ---------------------------------------------------------------- GEMM C = A * B^T
// 128x128 tile, BK=32, 4 waves (2x2 of 64x64), 4x4 16x16x32 frags/wave.
// Staging via global_load_lds width=16 into linear LDS [128][32].
// MODE 0: QKV — B/out by blockIdx.y>>3, out bf16 ld 1024
// MODE 1: split-K partial — P = (float*)o0 + z*seg; P[gr*1024+gc] = acc
// MODE 2: FFN1 — out bf16 = relu(acc + bias), ld 4096
template<int MODE>
__global__ __launch_bounds__(256) void gemm_bt(
    const short* __restrict__ A, int M, int K, int klen,
    const short* __restrict__ B0, const short* __restrict__ B1, const short* __restrict__ B2,
    const float* __restrict__ bias,
    void* __restrict__ o0, void* __restrict__ o1, void* __restrict__ o2, int seg)
{
    const int tid = threadIdx.x;
    const int w = tid >> 6, l = tid & 63;
    const int lr = l & 15, lh = l >> 4;
    const int m0 = blockIdx.x * 128;
    int ntile = blockIdx.y, nsel = 0;
    const short* B = B0;
    if (MODE == 0) { nsel = ntile >> 3; ntile &= 7; B = nsel == 0 ? B0 : (nsel == 1 ? B1 : B2); }
    const int n0 = ntile * 128;
    const int wr = (w >> 1) * 64, wc = (w & 1) * 64;
    const int kbase = blockIdx.z * klen;

    __shared__ __align__(16) short As[128 * 32];   // linear — required by global_load_lds
    __shared__ __align__(16) short Bs[128 * 32];

    // staging geometry: wave w covers rows w*32 .. w*32+31 (two 16-row / 1KB segments)
    const int srow = w * 32 + (l >> 2);
    const int scol = (l & 3) * 8;
    int ar0 = m0 + srow;      if (ar0 > M - 1) ar0 = M - 1;
    int ar1 = m0 + srow + 16; if (ar1 > M - 1) ar1 = M - 1;
    const short* ga0 = A + (size_t)ar0 * K + scol;
    const short* ga1 = A + (size_t)ar1 * K + scol;
    const short* gb0 = B + (size_t)(n0 + srow) * K + scol;
    const short* gb1 = B + (size_t)(n0 + srow + 16) * K + scol;
    short* la0 = As + (w * 32) * 32;
    short* la1 = As + (w * 32 + 16) * 32;
    short* lb0 = Bs + (w * 32) * 32;
    short* lb1 = Bs + (w * 32 + 16) * 32;

    f32x4 acc[4][4];
#pragma unroll
    for (int m = 0; m < 4; ++m)
#pragma unroll
        for (int n = 0; n < 4; ++n) acc[m][n] = (f32x4){0.f, 0.f, 0.f, 0.f};

    for (int k0 = kbase; k0 < kbase + klen; k0 += 32) {
        gll16(ga0 + k0, la0);
        gll16(ga1 + k0, la1);
        gll16(gb0 + k0, lb0);
        gll16(gb1 + k0, lb1);
        __syncthreads();           // drains vmcnt before barrier (compiler-inserted)
        short8 af[4], bfr[4];
#pragma unroll
        for (int m = 0; m < 4; ++m)
            af[m] = *(const short8*)(As + (wr + m * 16 + lr) * 32 + lh * 8);
#pragma unroll
        for (int n = 0; n < 4; ++n)
            bfr[n] = *(const short8*)(Bs + (wc + n * 16 + lr) * 32 + lh * 8);
#pragma unroll
        for (int m = 0; m < 4; ++m)
#pragma unroll
            for (int n = 0; n < 4; ++n)
                acc[m][n] = __builtin_amdgcn_mfma_f32_16x16x32_bf16(af[m], bfr[n], acc[m][n], 0, 0, 0);
        __syncthreads();
    }

#pragma unroll
    for (int m = 0; m < 4; ++m) {
#pragma unroll
        for (int n = 0; n < 4; ++n) {
            int gc = n0 + wc + n * 16 + lr;
#pragma unroll
            for (int j = 0; j < 4; ++j) {
                int gr = m0 + wr + m * 16 + lh * 4 + j;
                if (gr >= M) continue;
                float val = acc[m][n][j];
                if (MODE == 0) {
                    short* o = (short*)(nsel == 0 ? o0 : (nsel == 1 ? o1 : o2));
                    o[(size_t)gr * 1024 + gc] = f2bf(val);
                } else if (MODE == 1) {
                    float* P = (float*)o0 + (size_t)blockIdx.z * (size_t)seg;
                    P[(size_t)gr * 1024 + gc] = val;
                } else {
                    val += bias[gc];
                    val = val > 0.f ? val : 0.f;
                    ((short*)o0)[(size_t)gr * 4096 + gc] = f2bf(val);
                }
            }
        }
    }
}

// ---------------------------------------------------------------- split-K reduces
// x1 = x + P[i] + P[i + 4227072]
__global__ __launch_bounds__(256) void reduce_wo(
    const float* __restrict__ x, const float* __restrict__ P, float* __restrict__ x1)
{
    size_t i = ((size_t)blockIdx.x * 256 + threadIdx.x) * 4;
    float4 a  = *(const float4*)(x + i);
    float4 p0 = *(const float4*)(P + i);
    float4 p1 = *(const float4*)(P + i + 4227072);
    float4 o;
    o.x = a.x + p0.x + p1.x; o.y = a.y + p0.y + p1.y;
    o.z = a.z + p0.z + p1.z; o.w = a.w + p0.w + p1.w;
    *(float4*)(x1 + i) = o;
}

// out[reg row g] = x1[g] + P0 + P1 + bias
__global__ __launch_bounds__(256) void reduce_f2reg(
    const float* __restrict__ x1, const float* __restrict__ P,
    const float* __restrict__ bias, float* __restrict__ out)
{
    size_t i = ((size_t)blockIdx.x * 256 + threadIdx.x) * 4;
    int gr = (int)(i >> 10), c = (int)(i & 1023);
    size_t g = (size_t)((gr >> 11) * 2064 + 16 + (gr & 2047)) * 1024 + c;
    float4 p0 = *(const float4*)(P + i);
    float4 p1 = *(const float4*)(P + i + 4194304);
    float4 r  = *(const float4*)(x1 + g);
    float4 bb = *(const float4*)(bias + c);
    float4 o;
    o.x = r.x + p0.x + p1.x + bb.x; o.y = r.y + p0.y + p1.y + bb.y;
    o.z = r.z + p0.z + p1.z + bb.z; o.w = r.w + p0.w + p1.w + bb.w;
    *(float4*)(out + g) = o;
}

// out[sum row g] = x1[g] + sum_{s<16} P[s*32768 + i] + bias
__global__ __launch_bounds__(256) void reduce_f2sum(
    const float* __restrict__ x1, const float* __restrict__ P,
    const float* __restrict__ bias, float* __restrict__ out)
{
    int i = (blockIdx.x * 256 + threadIdx.x) * 4;   // over 32*1024
    int gr = i >> 10, c = i & 1023;
    size_t g = (size_t)((gr >> 4) * 2064 + (gr & 15)) * 1024 + c;
    float4 r  = *(const float4*)(x1 + g);
    float4 bb = *(const float4*)(bias + c);
    float ox = r.x + bb.x, oy = r.y + bb.y, oz = r.z + bb.z, ow = r.w + bb.w;
#pragma unroll
    for (int s = 0; s < 16; ++s) {
        float4 p = *(const float4*)(P + s * 32768 + i);
        ox += p.x; oy += p.y; oz += p.z; ow += p.w;
    }
    float4 o; o.x = ox; o.y = oy; o.z = oz; o.w = ow;
    *(float4*)(out + g) = o;
}

// ---------------------------------------------------------------- chunk attention (reg queries)
__global__ __launch_bounds__(256) void attn_reg(
    const short* __restrict__ q, const short* __restrict__ k,
    const short* __restrict__ v, short* __restrict__ ctx)
{
    __shared__ __align__(16) short Pl[128 * 168];  // P[128][160+8]; first aliased K[144][72]
    __shared__ __align__(16) short Vt[64 * 168];   // V^T [64][160+8]
    short* Kl = Pl;

    const int tid = threadIdx.x;
    const int w = tid >> 6, l = tid & 63, lr = l & 15, lh = l >> 4;
    const int c = blockIdx.x, h = blockIdx.y, b = blockIdx.z;
    const int hc = h * 64;
    const size_t rowq0 = (size_t)b * 2064 + 16 + (size_t)c * 128;

    for (int ch = tid; ch < 1152; ch += 256) {
        int row = ch >> 3, kk = (ch & 7) << 3;
        size_t grow = (row < 16) ? ((size_t)b * 2064 + row) : (rowq0 + row - 16);
        *(int4*)(Kl + row * 72 + kk) = *(const int4*)(k + grow * 1024 + hc + kk);
    }
    for (int ch = tid; ch < 1152; ch += 256) {
        int j = ch % 144, db = ch / 144;
        size_t grow = (j < 16) ? ((size_t)b * 2064 + j) : (rowq0 + j - 16);
        short8 dv = *(const short8*)(v + grow * 1024 + hc + db * 8);
#pragma unroll
        for (int i = 0; i < 8; ++i) Vt[(db * 8 + i) * 168 + j] = dv[i];
    }
    for (int idx = tid; idx < 1024; idx += 256) {
        int d = idx >> 4, jj = 144 + (idx & 15);
        Vt[d * 168 + jj] = 0;
    }
    __syncthreads();

    short8 qf[2][2];
#pragma unroll
    for (int m = 0; m < 2; ++m) {
        size_t grow = rowq0 + w * 32 + m * 16 + lr;
#pragma unroll
        for (int ks = 0; ks < 2; ++ks)
            qf[m][ks] = *(const short8*)(q + grow * 1024 + hc + ks * 32 + lh * 8);
    }

    f32x4 s[2][9];
#pragma unroll
    for (int m = 0; m < 2; ++m)
#pragma unroll
        for (int n = 0; n < 9; ++n) s[m][n] = (f32x4){0.f, 0.f, 0.f, 0.f};
#pragma unroll
    for (int n = 0; n < 9; ++n) {
        const short* kr = Kl + (n * 16 + lr) * 72;
        short8 k0 = *(const short8*)(kr + lh * 8);
        short8 k1 = *(const short8*)(kr + 32 + lh * 8);
        s[0][n] = __builtin_amdgcn_mfma_f32_16x16x32_bf16(qf[0][0], k0, s[0][n], 0, 0, 0);
        s[0][n] = __builtin_amdgcn_mfma_f32_16x16x32_bf16(qf[0][1], k1, s[0][n], 0, 0, 0);
        s[1][n] = __builtin_amdgcn_mfma_f32_16x16x32_bf16(qf[1][0], k0, s[1][n], 0, 0, 0);
        s[1][n] = __builtin_amdgcn_mfma_f32_16x16x32_bf16(qf[1][1], k1, s[1][n], 0, 0, 0);
    }

    float inv_[2][4];
#pragma unroll
    for (int m = 0; m < 2; ++m) {
#pragma unroll
        for (int j = 0; j < 4; ++j) {
            int p = w * 32 + m * 16 + lh * 4 + j;
            float best = -1e30f;
            float e[9];
#pragma unroll
            for (int n = 0; n < 9; ++n) {
                int kk = n * 16 + lr;
                bool vis = (kk < 16) ? (kk < c) : (kk - 16 <= p);
                float val = vis ? s[m][n][j] * 0.125f : -1e30f;
                e[n] = val;
                best = fmaxf(best, val);
            }
#pragma unroll
            for (int off = 1; off < 16; off <<= 1) best = fmaxf(best, __shfl_xor(best, off));
            float sm = 0.f;
#pragma unroll
            for (int n = 0; n < 9; ++n) {
                float ex = __expf(e[n] - best);
                s[m][n][j] = ex;
                sm += ex;
            }
#pragma unroll
            for (int off = 1; off < 16; off <<= 1) sm += __shfl_xor(sm, off);
            inv_[m][j] = 1.0f / sm;
        }
    }

    __syncthreads();
#pragma unroll
    for (int m = 0; m < 2; ++m)
#pragma unroll
        for (int n = 0; n < 9; ++n)
#pragma unroll
            for (int j = 0; j < 4; ++j)
                Pl[(w * 32 + m * 16 + lh * 4 + j) * 168 + n * 16 + lr] = f2bf(s[m][n][j]);
    for (int idx = l; idx < 512; idx += 64) {
        int rr = idx >> 4, kkp = 144 + (idx & 15);
        Pl[(w * 32 + rr) * 168 + kkp] = 0;
    }
    __syncthreads();

    f32x4 dacc[2][4];
#pragma unroll
    for (int m = 0; m < 2; ++m)
#pragma unroll
        for (int n = 0; n < 4; ++n) dacc[m][n] = (f32x4){0.f, 0.f, 0.f, 0.f};
#pragma unroll
    for (int ks = 0; ks < 5; ++ks) {
        int kk0 = ks * 32;
        short8 pa[2];
#pragma unroll
        for (int m = 0; m < 2; ++m)
            pa[m] = *(const short8*)(Pl + (w * 32 + m * 16 + lr) * 168 + kk0 + lh * 8);
#pragma unroll
        for (int n = 0; n < 4; ++n) {
            short8 vb = *(const short8*)(Vt + (n * 16 + lr) * 168 + kk0 + lh * 8);
            dacc[0][n] = __builtin_amdgcn_mfma_f32_16x16x32_bf16(pa[0], vb, dacc[0][n], 0, 0, 0);
            dacc[1][n] = __builtin_amdgcn_mfma_f32_16x16x32_bf16(pa[1], vb, dacc[1][n], 0, 0, 0);
        }
    }

#pragma unroll
    for (int m = 0; m < 2; ++m)
#pragma unroll
        for (int n = 0; n < 4; ++n)
#pragma unroll
            for (int j = 0; j < 4; ++j) {
                int p = w * 32 + m * 16 + lh * 4 + j;
                ctx[(rowq0 + p) * 1024 + hc + n * 16 + lr] = f2bf(dacc[m][n][j] * inv_[m][j]);
            }
}

// ---------------------------------------------------------------- sum-token attention
__global__ __launch_bounds__(64) void attn_sum(
    const short* __restrict__ q, const short* __restrict__ k,
    const short* __restrict__ v, short* __restrict__ ctx)
{
    int idx = blockIdx.x;
    int b = idx >> 8, h = (idx >> 4) & 15, s = idx & 15;
    int l = threadIdx.x;
    int hc = h * 64;
    size_t qrow = (size_t)b * 2064 + s;
    __shared__ float qv[64];
    __shared__ float pp[192];
    qv[l] = bf2f(q[qrow * 1024 + hc + l]);
    __syncthreads();
    float sc[3];
#pragma unroll
    for (int i = 0; i < 3; ++i) {
        int j = l + i * 64;
        float t = -1e30f;
        if (j < 144 && (j >= 16 || j <= s)) {
            size_t kr = (j < 16) ? ((size_t)b * 2064 + j)
                                 : ((size_t)b * 2064 + 16 + (size_t)s * 128 + (j - 16));
            const short* kp = k + kr * 1024 + hc;
            float acc = 0.f;
            for (int d = 0; d < 64; ++d) acc += qv[d] * bf2f(kp[d]);
            t = acc * 0.125f;
        }
        sc[i] = t;
    }
    float mx = fmaxf(sc[0], fmaxf(sc[1], sc[2]));
#pragma unroll
    for (int off = 1; off < 64; off <<= 1) mx = fmaxf(mx, __shfl_xor(mx, off));
    float sm = 0.f;
#pragma unroll
    for (int i = 0; i < 3; ++i) {
        float ex = (sc[i] > -1e29f) ? __expf(sc[i] - mx) : 0.f;
        pp[l + i * 64] = ex;
        sm += ex;
    }
#pragma unroll
    for (int off = 1; off < 64; off <<= 1) sm += __shfl_xor(sm, off);
    __syncthreads();
    float invs = 1.0f / sm;
    float acc = 0.f;
    for (int j = 0; j < 144; ++j) {
        float pj = pp[j];
        size_t vr = (j < 16) ? ((size_t)b * 2064 + j)
                             : ((size_t)b * 2064 + 16 + (size_t)s * 128 + (j - 16));
        acc += pj * bf2f(v[vr * 1024 + hc + l]);
    }
    ctx[qrow * 1024 + hc + l] = f2bf(acc * invs);
}

// ---------------------------------------------------------------- launch
extern "C" void kernel_launch(void* const* d_in, const int* in_sizes, int n_in,
                              void* d_out, int out_size, void* d_ws, size_t ws_size,
                              hipStream_t stream) {
    const float* x    = (const float*)d_in[0];
    const float* wq   = (const float*)d_in[1];
    const float* wk   = (const float*)d_in[2];
    const float* wv   = (const float*)d_in[3];
    const float* wo   = (const float*)d_in[4];
    const float* lsg  = (const float*)d_in[5];
    const float* lsb  = (const float*)d_in[6];
    const float* lrg  = (const float*)d_in[7];
    const float* lrb  = (const float*)d_in[8];
    const float* sf1w = (const float*)d_in[9];
    const float* sf1b = (const float*)d_in[10];
    const float* sf2w = (const float*)d_in[11];
    const float* sf2b = (const float*)d_in[12];
    const float* rf1w = (const float*)d_in[13];
    const float* rf1b = (const float*)d_in[14];
    const float* rf2w = (const float*)d_in[15];
    const float* rf2b = (const float*)d_in[16];
    const float* fsg  = (const float*)d_in[17];
    const float* fsb  = (const float*)d_in[18];
    const float* frg  = (const float*)d_in[19];
    const float* frb  = (const float*)d_in[20];
    float* out = (float*)d_out;

    char* ws = (char*)d_ws;
    // bf16 weights: 20M shorts = 40 MB (bytes [0, 41943040))
    short* wbf   = (short*)ws;
    short* wq_b  = wbf;
    short* wk_b  = wbf + 1048576;
    short* wv_b  = wbf + 2097152;
    short* wo_b  = wbf + 3145728;
    short* f1s_b = wbf + 4194304;
    short* f2s_b = wbf + 8388608;
    short* f1r_b = wbf + 12582912;
    short* f2r_b = wbf + 16777216;
    // region1 [41943040, 50397184): h_all | later h2_reg+h2_sum | Pwo(part) | Psum
    short* h_all  = (short*)(ws + 41943040);
    short* h2_reg = h_all;
    short* h2_sum = (short*)(ws + 41943040 + 8388608);
    float* Pwo    = (float*)(ws + 41943040);   // 2 x 4128*1024 f32 = 33.8 MB (spans into region2)
    float* Psum   = (float*)(ws + 41943040);   // 16 x 32768 f32 = 2 MB
    // region2 [50397184, 84213760): q,k,v,ctx | later f1_reg + f1_sum
    short* qb   = (short*)(ws + 50397184);
    short* kb   = qb + 4227072;
    short* vb   = kb + 4227072;
    short* ctxb = vb + 4227072;
    short* f1_reg = qb;
    short* f1_sum = qb + 16777216;
    // FFN2-reg partials overwrite dead weights: 2 x 4096*1024 f32 = 32 MB at [0, 33554432)
    float* Pf2 = (float*)ws;
    // x1 fp32 residual at [84213760, 101122048)
    float* x1 = (float*)(ws + 84213760);

    // 1. weights -> bf16
    cvt_w<<<20480, 256, 0, stream>>>(wq, wk, wv, wo, sf1w, sf2w, rf1w, rf2w, wbf);
    // 2. pre-attn LN
    ln_k<0><<<4128, 256, 0, stream>>>(x, lsg, lsb, lrg, lrb, h_all, nullptr, nullptr);
    // 3. fused QKV
    gemm_bt<0><<<dim3(33, 24, 1), 256, 0, stream>>>(h_all, 4128, 1024, 1024,
        wq_b, wk_b, wv_b, nullptr, qb, kb, vb, 0);
    // 4. attention
    attn_reg<<<dim3(16, 16, 2), 256, 0, stream>>>(qb, kb, vb, ctxb);
    attn_sum<<<512, 64, 0, stream>>>(qb, kb, vb, ctxb);
    // 5. W_O split-K=2 -> Pwo, then x1 = x + P0 + P1
    gemm_bt<1><<<dim3(33, 8, 2), 256, 0, stream>>>(ctxb, 4128, 1024, 512,
        wo_b, nullptr, nullptr, nullptr, Pwo, nullptr, nullptr, 4227072);
    reduce_wo<<<4128, 256, 0, stream>>>(x, Pwo, x1);
    // 6. pre-FFN LN (scatter; overwrites Pwo region — already consumed)
    ln_k<1><<<4128, 256, 0, stream>>>(x1, fsg, fsb, frg, frb, nullptr, h2_sum, h2_reg);
    // 7. FFN1
    gemm_bt<2><<<dim3(32, 32, 1), 256, 0, stream>>>(h2_reg, 4096, 1024, 1024,
        f1r_b, nullptr, nullptr, rf1b, f1_reg, nullptr, nullptr, 0);
    gemm_bt<2><<<dim3(1, 32, 1), 256, 0, stream>>>(h2_sum, 32, 1024, 1024,
        f1s_b, nullptr, nullptr, sf1b, f1_sum, nullptr, nullptr, 0);
    // 8. FFN2-sum split-K=16 -> Psum, reduce -> out (sum rows)
    gemm_bt<1><<<dim3(1, 8, 16), 256, 0, stream>>>(f1_sum, 32, 4096, 256,
        f2s_b, nullptr, nullptr, nullptr, Psum, nullptr, nullptr, 32768);
    reduce_f2sum<<<32, 256, 0, stream>>>(x1, Psum, sf2b, out);
    // 9. FFN2-reg split-K=2 -> Pf2 (over dead wq..f1r weights), reduce -> out (reg rows)
    gemm_bt<1><<<dim3(32, 8, 2), 256, 0, stream>>>(f1_reg, 4096, 4096, 2048,
        f2r_b, nullptr, nullptr, nullptr, Pf2, nullptr, nullptr, 4194304);
    reduce_f2reg<<<4096, 256, 0, stream>>>(x1, Pf2, rf2b, out);
}

// Round 5
// 302.660 us; speedup vs baseline: 1.5116x; 1.0963x over previous
//
#include <hip/hip_runtime.h>
#include <stdint.h>

typedef __attribute__((ext_vector_type(8))) short short8;
typedef __attribute__((ext_vector_type(4))) float f32x4;

__device__ __forceinline__ float bf2f(short s) {
    union { unsigned u; float f; } c;
    c.u = ((unsigned)(unsigned short)s) << 16;
    return c.f;
}
__device__ __forceinline__ short f2bf(float f) {
    union { float f; unsigned u; } c; c.f = f;
    unsigned u = c.u + 0x7fffu + ((c.u >> 16) & 1u);
    return (short)(u >> 16);
}
// async global->LDS, 16B per lane; lds dst wave-uniform base (HW adds lane*16)
__device__ __forceinline__ void gll16(const short* g, short* l) {
    __builtin_amdgcn_global_load_lds(
        (const __attribute__((address_space(1))) unsigned int*)g,
        (__attribute__((address_space(3))) unsigned int*)l, 16, 0, 0);
}

// ---------------------------------------------------------------- weights cvt
__global__ __launch_bounds__(256) void cvt_w(
    const float* __restrict__ wq, const float* __restrict__ wk,
    const float* __restrict__ wv, const float* __restrict__ wo,
    const float* __restrict__ f1s, const float* __restrict__ f2s,
    const float* __restrict__ f1r, const float* __restrict__ f2r,
    short* __restrict__ dst)
{
    size_t i = ((size_t)blockIdx.x * 256 + threadIdx.x) * 4;
    const float* src; size_t off;
    if (i < 4194304) {
        int seg = (int)(i >> 20);
        src = seg == 0 ? wq : seg == 1 ? wk : seg == 2 ? wv : wo;
        off = i & 1048575;
    } else {
        size_t ii = i - 4194304;
        int seg = (int)(ii >> 22);
        src = seg == 0 ? f1s : seg == 1 ? f2s : seg == 2 ? f1r : f2r;
        off = ii & 4194303;
    }
    float4 v = *(const float4*)(src + off);
    short4 o;
    o.x = f2bf(v.x); o.y = f2bf(v.y); o.z = f2bf(v.z); o.w = f2bf(v.w);
    *(short4*)(dst + i) = o;
}

// ---------------------------------------------------------------- layernorm
// PHASE 0: out_all = LN(x)                      (pre-attention)
// PHASE 1: x1 = x + P0 + P1 (WO split-K reduce); scatter LN(x1) to out_s/out_r
//          NOTE: out_s/out_r must NOT alias P (producer/consumer fused here).
template<int PHASE>
__global__ __launch_bounds__(256) void ln_k(
    const float* __restrict__ xin, const float* __restrict__ P, float* __restrict__ x1out,
    const float* __restrict__ g_sum, const float* __restrict__ b_sum,
    const float* __restrict__ g_reg, const float* __restrict__ b_reg,
    short* __restrict__ out_all, short* __restrict__ out_s, short* __restrict__ out_r)
{
    int row = blockIdx.x;
    int b = row / 2064, t = row - b * 2064;
    int tid = threadIdx.x;
    int c = tid * 4;
    size_t base = (size_t)row * 1024 + c;
    float4 v = *(const float4*)(xin + base);
    if (PHASE == 1) {
        float4 p0 = *(const float4*)(P + base);
        float4 p1 = *(const float4*)(P + base + 4227072);
        v.x += p0.x + p1.x; v.y += p0.y + p1.y;
        v.z += p0.z + p1.z; v.w += p0.w + p1.w;
        *(float4*)(x1out + base) = v;
    }
    float s = v.x + v.y + v.z + v.w;
#pragma unroll
    for (int off = 1; off < 64; off <<= 1) s += __shfl_xor(s, off);
    __shared__ float red[8];
    if ((tid & 63) == 0) red[tid >> 6] = s;
    __syncthreads();
    float mu = (red[0] + red[1] + red[2] + red[3]) * (1.0f / 1024.0f);
    float a0 = v.x - mu, a1 = v.y - mu, a2 = v.z - mu, a3 = v.w - mu;
    float qq = a0 * a0 + a1 * a1 + a2 * a2 + a3 * a3;
#pragma unroll
    for (int off = 1; off < 64; off <<= 1) qq += __shfl_xor(qq, off);
    if ((tid & 63) == 0) red[4 + (tid >> 6)] = qq;
    __syncthreads();
    float var = (red[4] + red[5] + red[6] + red[7]) * (1.0f / 1024.0f);
    float rs = rsqrtf(var + 1e-5f);
    const float* g  = (t < 16) ? g_sum : g_reg;
    const float* be = (t < 16) ? b_sum : b_reg;
    short4 o;
    o.x = f2bf(a0 * rs * g[c]     + be[c]);
    o.y = f2bf(a1 * rs * g[c + 1] + be[c + 1]);
    o.z = f2bf(a2 * rs * g[c + 2] + be[c + 2]);
    o.w = f2bf(a3 * rs * g[c + 3] + be[c + 3]);
    short* dst;
    if (PHASE == 0) dst = out_all + (size_t)row * 1024;
    else dst = (t < 16) ? (out_s + ((size_t)b * 16 + t) * 1024)
                        : (out_r + ((size_t)b * 2048 + (t - 16)) * 1024);
    *(short4*)(dst + c) = o;
}

// ---------------------------------------------------------------- GEMM C = A * B^T
// 128x128 tile, BK=32, 4 waves, double-buffered global_load_lds prefetch,
// ONE barrier per K-step (prefetch latency hides under ds_read+MFMA).
// MODE 0: QKV — B/out by blockIdx.y>>3, out bf16 ld 1024
// MODE 1: split-K partial — P[z*seg + gr*1024 + gc] = acc (f32)
// MODE 2: FFN1 — out bf16 = relu(acc + bias), ld 4096
template<int MODE>
__global__ __launch_bounds__(256) void gemm_bt(
    const short* __restrict__ A, int M, int K, int klen,
    const short* __restrict__ B0, const short* __restrict__ B1, const short* __restrict__ B2,
    const float* __restrict__ bias,
    void* __restrict__ o0, void* __restrict__ o1, void* __restrict__ o2, int seg)
{
    const int tid = threadIdx.x;
    const int w = tid >> 6, l = tid & 63;
    const int lr = l & 15, lh = l >> 4;
    const int m0 = blockIdx.x * 128;
    int ntile = blockIdx.y, nsel = 0;
    const short* B = B0;
    if (MODE == 0) { nsel = ntile >> 3; ntile &= 7; B = nsel == 0 ? B0 : (nsel == 1 ? B1 : B2); }
    const int n0 = ntile * 128;
    const int wr = (w >> 1) * 64, wc = (w & 1) * 64;
    const int kbase = blockIdx.z * klen;

    __shared__ __align__(16) short As[2 * 4096];   // [buf][128][32] linear
    __shared__ __align__(16) short Bs[2 * 4096];

    // staging: wave w covers rows w*32..w*32+31 (two 16-row/1KB segments per matrix)
    const int srow = w * 32 + (l >> 2);
    const int scol = (l & 3) * 8;
    int ar0 = m0 + srow;      if (ar0 > M - 1) ar0 = M - 1;
    int ar1 = m0 + srow + 16; if (ar1 > M - 1) ar1 = M - 1;
    const short* ga0 = A + (size_t)ar0 * K + scol + kbase;
    const short* ga1 = A + (size_t)ar1 * K + scol + kbase;
    const short* gb0 = B + (size_t)(n0 + srow) * K + scol + kbase;
    const short* gb1 = B + (size_t)(n0 + srow + 16) * K + scol + kbase;
    const int lofs = (w * 32) * 32;   // wave-uniform LDS base (lane*16B added by HW)

    f32x4 acc[4][4];
#pragma unroll
    for (int m = 0; m < 4; ++m)
#pragma unroll
        for (int n = 0; n < 4; ++n) acc[m][n] = (f32x4){0.f, 0.f, 0.f, 0.f};

    // prologue: stage tile 0 into buf 0
    gll16(ga0, As + lofs);
    gll16(ga1, As + lofs + 512);
    gll16(gb0, Bs + lofs);
    gll16(gb1, Bs + lofs + 512);

    const int nk = klen >> 5;
    for (int t = 0; t < nk; ++t) {
        __syncthreads();            // drains own vmcnt (stage landed) + lgkmcnt; syncs waves
        const int cur = (t & 1) << 12;
        if (t + 1 < nk) {           // prefetch next tile into the other buffer
            const int nb = cur ^ 4096;
            const int k0 = (t + 1) * 32;
            gll16(ga0 + k0, As + nb + lofs);
            gll16(ga1 + k0, As + nb + lofs + 512);
            gll16(gb0 + k0, Bs + nb + lofs);
            gll16(gb1 + k0, Bs + nb + lofs + 512);
        }
        short8 af[4], bfr[4];
#pragma unroll
        for (int m = 0; m < 4; ++m)
            af[m] = *(const short8*)(As + cur + (wr + m * 16 + lr) * 32 + lh * 8);
#pragma unroll
        for (int n = 0; n < 4; ++n)
            bfr[n] = *(const short8*)(Bs + cur + (wc + n * 16 + lr) * 32 + lh * 8);
#pragma unroll
        for (int m = 0; m < 4; ++m)
#pragma unroll
            for (int n = 0; n < 4; ++n)
                acc[m][n] = __builtin_amdgcn_mfma_f32_16x16x32_bf16(af[m], bfr[n], acc[m][n], 0, 0, 0);
        // no second barrier: prefetch at iter t writes only buffer (t+1)&1, which
        // no wave reads during iter t; reads of buffer t&1 complete before the
        // iter-(t+1) barrier (lgkmcnt drain), so the next stage cannot race.
    }

#pragma unroll
    for (int m = 0; m < 4; ++m) {
#pragma unroll
        for (int n = 0; n < 4; ++n) {
            int gc = n0 + wc + n * 16 + lr;
#pragma unroll
            for (int j = 0; j < 4; ++j) {
                int gr = m0 + wr + m * 16 + lh * 4 + j;
                if (gr >= M) continue;
                float val = acc[m][n][j];
                if (MODE == 0) {
                    short* o = (short*)(nsel == 0 ? o0 : (nsel == 1 ? o1 : o2));
                    o[(size_t)gr * 1024 + gc] = f2bf(val);
                } else if (MODE == 1) {
                    float* P = (float*)o0 + (size_t)blockIdx.z * (size_t)seg;
                    P[(size_t)gr * 1024 + gc] = val;
                } else {
                    val += bias[gc];
                    val = val > 0.f ? val : 0.f;
                    ((short*)o0)[(size_t)gr * 4096 + gc] = f2bf(val);
                }
            }
        }
    }
}

// ---------------------------------------------------------------- split-K reduces
// out[reg row g] = x1[g] + P0 + P1 + bias
__global__ __launch_bounds__(256) void reduce_f2reg(
    const float* __restrict__ x1, const float* __restrict__ P,
    const float* __restrict__ bias, float* __restrict__ out)
{
    size_t i = ((size_t)blockIdx.x * 256 + threadIdx.x) * 4;
    int gr = (int)(i >> 10), c = (int)(i & 1023);
    size_t g = (size_t)((gr >> 11) * 2064 + 16 + (gr & 2047)) * 1024 + c;
    float4 p0 = *(const float4*)(P + i);
    float4 p1 = *(const float4*)(P + i + 4194304);
    float4 r  = *(const float4*)(x1 + g);
    float4 bb = *(const float4*)(bias + c);
    float4 o;
    o.x = r.x + p0.x + p1.x + bb.x; o.y = r.y + p0.y + p1.y + bb.y;
    o.z = r.z + p0.z + p1.z + bb.z; o.w = r.w + p0.w + p1.w + bb.w;
    *(float4*)(out + g) = o;
}

// out[sum row g] = x1[g] + sum_{s<16} P[s*32768 + i] + bias
__global__ __launch_bounds__(256) void reduce_f2sum(
    const float* __restrict__ x1, const float* __restrict__ P,
    const float* __restrict__ bias, float* __restrict__ out)
{
    int i = (blockIdx.x * 256 + threadIdx.x) * 4;   // over 32*1024
    int gr = i >> 10, c = i & 1023;
    size_t g = (size_t)((gr >> 4) * 2064 + (gr & 15)) * 1024 + c;
    float4 r  = *(const float4*)(x1 + g);
    float4 bb = *(const float4*)(bias + c);
    float ox = r.x + bb.x, oy = r.y + bb.y, oz = r.z + bb.z, ow = r.w + bb.w;
#pragma unroll
    for (int s = 0; s < 16; ++s) {
        float4 p = *(const float4*)(P + s * 32768 + i);
        ox += p.x; oy += p.y; oz += p.z; ow += p.w;
    }
    float4 o; o.x = ox; o.y = oy; o.z = oz; o.w = ow;
    *(float4*)(out + g) = o;
}

// ---------------------------------------------------------------- chunk attention (reg queries)
__global__ __launch_bounds__(256) void attn_reg(
    const short* __restrict__ q, const short* __restrict__ k,
    const short* __restrict__ v, short* __restrict__ ctx)
{
    __shared__ __align__(16) short Pl[128 * 168];  // P[128][160+8]; first aliased K[144][72]
    __shared__ __align__(16) short Vt[64 * 168];   // V^T [64][160+8]
    short* Kl = Pl;

    const int tid = threadIdx.x;
    const int w = tid >> 6, l = tid & 63, lr = l & 15, lh = l >> 4;
    const int c = blockIdx.x, h = blockIdx.y, b = blockIdx.z;
    const int hc = h * 64;
    const size_t rowq0 = (size_t)b * 2064 + 16 + (size_t)c * 128;

    for (int ch = tid; ch < 1152; ch += 256) {
        int row = ch >> 3, kk = (ch & 7) << 3;
        size_t grow = (row < 16) ? ((size_t)b * 2064 + row) : (rowq0 + row - 16);
        *(int4*)(Kl + row * 72 + kk) = *(const int4*)(k + grow * 1024 + hc + kk);
    }
    for (int ch = tid; ch < 1152; ch += 256) {
        int j = ch % 144, db = ch / 144;
        size_t grow = (j < 16) ? ((size_t)b * 2064 + j) : (rowq0 + j - 16);
        short8 dv = *(const short8*)(v + grow * 1024 + hc + db * 8);
#pragma unroll
        for (int i = 0; i < 8; ++i) Vt[(db * 8 + i) * 168 + j] = dv[i];
    }
    for (int idx = tid; idx < 1024; idx += 256) {
        int d = idx >> 4, jj = 144 + (idx & 15);
        Vt[d * 168 + jj] = 0;
    }
    __syncthreads();

    short8 qf[2][2];
#pragma unroll
    for (int m = 0; m < 2; ++m) {
        size_t grow = rowq0 + w * 32 + m * 16 + lr;
#pragma unroll
        for (int ks = 0; ks < 2; ++ks)
            qf[m][ks] = *(const short8*)(q + grow * 1024 + hc + ks * 32 + lh * 8);
    }

    f32x4 s[2][9];
#pragma unroll
    for (int m = 0; m < 2; ++m)
#pragma unroll
        for (int n = 0; n < 9; ++n) s[m][n] = (f32x4){0.f, 0.f, 0.f, 0.f};
#pragma unroll
    for (int n = 0; n < 9; ++n) {
        const short* kr = Kl + (n * 16 + lr) * 72;
        short8 k0 = *(const short8*)(kr + lh * 8);
        short8 k1 = *(const short8*)(kr + 32 + lh * 8);
        s[0][n] = __builtin_amdgcn_mfma_f32_16x16x32_bf16(qf[0][0], k0, s[0][n], 0, 0, 0);
        s[0][n] = __builtin_amdgcn_mfma_f32_16x16x32_bf16(qf[0][1], k1, s[0][n], 0, 0, 0);
        s[1][n] = __builtin_amdgcn_mfma_f32_16x16x32_bf16(qf[1][0], k0, s[1][n], 0, 0, 0);
        s[1][n] = __builtin_amdgcn_mfma_f32_16x16x32_bf16(qf[1][1], k1, s[1][n], 0, 0, 0);
    }

    float inv_[2][4];
#pragma unroll
    for (int m = 0; m < 2; ++m) {
#pragma unroll
        for (int j = 0; j < 4; ++j) {
            int p = w * 32 + m * 16 + lh * 4 + j;
            float best = -1e30f;
            float e[9];
#pragma unroll
            for (int n = 0; n < 9; ++n) {
                int kk = n * 16 + lr;
                bool vis = (kk < 16) ? (kk < c) : (kk - 16 <= p);
                float val = vis ? s[m][n][j] * 0.125f : -1e30f;
                e[n] = val;
                best = fmaxf(best, val);
            }
#pragma unroll
            for (int off = 1; off < 16; off <<= 1) best = fmaxf(best, __shfl_xor(best, off));
            float sm = 0.f;
#pragma unroll
            for (int n = 0; n < 9; ++n) {
                float ex = __expf(e[n] - best);
                s[m][n][j] = ex;
                sm += ex;
            }
#pragma unroll
            for (int off = 1; off < 16; off <<= 1) sm += __shfl_xor(sm, off);
            inv_[m][j] = 1.0f / sm;
        }
    }

    __syncthreads();
#pragma unroll
    for (int m = 0; m < 2; ++m)
#pragma unroll
        for (int n = 0; n < 9; ++n)
#pragma unroll
            for (int j = 0; j < 4; ++j)
                Pl[(w * 32 + m * 16 + lh * 4 + j) * 168 + n * 16 + lr] = f2bf(s[m][n][j]);
    for (int idx = l; idx < 512; idx += 64) {
        int rr = idx >> 4, kkp = 144 + (idx & 15);
        Pl[(w * 32 + rr) * 168 + kkp] = 0;
    }
    __syncthreads();

    f32x4 dacc[2][4];
#pragma unroll
    for (int m = 0; m < 2; ++m)
#pragma unroll
        for (int n = 0; n < 4; ++n) dacc[m][n] = (f32x4){0.f, 0.f, 0.f, 0.f};
#pragma unroll
    for (int ks = 0; ks < 5; ++ks) {
        int kk0 = ks * 32;
        short8 pa[2];
#pragma unroll
        for (int m = 0; m < 2; ++m)
            pa[m] = *(const short8*)(Pl + (w * 32 + m * 16 + lr) * 168 + kk0 + lh * 8);
#pragma unroll
        for (int n = 0; n < 4; ++n) {
            short8 vb = *(const short8*)(Vt + (n * 16 + lr) * 168 + kk0 + lh * 8);
            dacc[0][n] = __builtin_amdgcn_mfma_f32_16x16x32_bf16(pa[0], vb, dacc[0][n], 0, 0, 0);
            dacc[1][n] = __builtin_amdgcn_mfma_f32_16x16x32_bf16(pa[1], vb, dacc[1][n], 0, 0, 0);
        }
    }

#pragma unroll
    for (int m = 0; m < 2; ++m)
#pragma unroll
        for (int n = 0; n < 4; ++n)
#pragma unroll
            for (int j = 0; j < 4; ++j) {
                int p = w * 32 + m * 16 + lh * 4 + j;
                ctx[(rowq0 + p) * 1024 + hc + n * 16 + lr] = f2bf(dacc[m][n][j] * inv_[m][j]);
            }
}

// ---------------------------------------------------------------- sum-token attention
__global__ __launch_bounds__(64) void attn_sum(
    const short* __restrict__ q, const short* __restrict__ k,
    const short* __restrict__ v, short* __restrict__ ctx)
{
    int idx = blockIdx.x;
    int b = idx >> 8, h = (idx >> 4) & 15, s = idx & 15;
    int l = threadIdx.x;
    int hc = h * 64;
    size_t qrow = (size_t)b * 2064 + s;
    __shared__ float qv[64];
    __shared__ float pp[192];
    qv[l] = bf2f(q[qrow * 1024 + hc + l]);
    __syncthreads();
    float sc[3];
#pragma unroll
    for (int i = 0; i < 3; ++i) {
        int j = l + i * 64;
        float t = -1e30f;
        if (j < 144 && (j >= 16 || j <= s)) {
            size_t kr = (j < 16) ? ((size_t)b * 2064 + j)
                                 : ((size_t)b * 2064 + 16 + (size_t)s * 128 + (j - 16));
            const short* kp = k + kr * 1024 + hc;
            float acc = 0.f;
            for (int d = 0; d < 64; ++d) acc += qv[d] * bf2f(kp[d]);
            t = acc * 0.125f;
        }
        sc[i] = t;
    }
    float mx = fmaxf(sc[0], fmaxf(sc[1], sc[2]));
#pragma unroll
    for (int off = 1; off < 64; off <<= 1) mx = fmaxf(mx, __shfl_xor(mx, off));
    float sm = 0.f;
#pragma unroll
    for (int i = 0; i < 3; ++i) {
        float ex = (sc[i] > -1e29f) ? __expf(sc[i] - mx) : 0.f;
        pp[l + i * 64] = ex;
        sm += ex;
    }
#pragma unroll
    for (int off = 1; off < 64; off <<= 1) sm += __shfl_xor(sm, off);
    __syncthreads();
    float invs = 1.0f / sm;
    float acc = 0.f;
    for (int j = 0; j < 144; ++j) {
        float pj = pp[j];
        size_t vr = (j < 16) ? ((size_t)b * 2064 + j)
                             : ((size_t)b * 2064 + 16 + (size_t)s * 128 + (j - 16));
        acc += pj * bf2f(v[vr * 1024 + hc + l]);
    }
    ctx[qrow * 1024 + hc + l] = f2bf(acc * invs);
}

// ---------------------------------------------------------------- launch
extern "C" void kernel_launch(void* const* d_in, const int* in_sizes, int n_in,
                              void* d_out, int out_size, void* d_ws, size_t ws_size,
                              hipStream_t stream) {
    const float* x    = (const float*)d_in[0];
    const float* wq   = (const float*)d_in[1];
    const float* wk   = (const float*)d_in[2];
    const float* wv   = (const float*)d_in[3];
    const float* wo   = (const float*)d_in[4];
    const float* lsg  = (const float*)d_in[5];
    const float* lsb  = (const float*)d_in[6];
    const float* lrg  = (const float*)d_in[7];
    const float* lrb  = (const float*)d_in[8];
    const float* sf1w = (const float*)d_in[9];
    const float* sf1b = (const float*)d_in[10];
    const float* sf2w = (const float*)d_in[11];
    const float* sf2b = (const float*)d_in[12];
    const float* rf1w = (const float*)d_in[13];
    const float* rf1b = (const float*)d_in[14];
    const float* rf2w = (const float*)d_in[15];
    const float* rf2b = (const float*)d_in[16];
    const float* fsg  = (const float*)d_in[17];
    const float* fsb  = (const float*)d_in[18];
    const float* frg  = (const float*)d_in[19];
    const float* frb  = (const float*)d_in[20];
    float* out = (float*)d_out;

    char* ws = (char*)d_ws;
    // ---- byte-range liveness map (all offsets in bytes) ----
    // weights bf16 [0, 41943040): wq[0,2M) wk[2M,4M) wv[4M,6M) wo[6M,8M)
    //   f1s[8388608,16777216) f2s[16777216,25165824) f1r[25165824,33554432) f2r[33554432,41943040)
    short* wbf   = (short*)ws;
    short* wq_b  = wbf;
    short* wk_b  = wbf + 1048576;
    short* wv_b  = wbf + 2097152;
    short* wo_b  = wbf + 3145728;
    short* f1s_b = wbf + 4194304;
    short* f2s_b = wbf + 8388608;
    short* f1r_b = wbf + 12582912;
    short* f2r_b = wbf + 16777216;
    // h_all [41943040, 50397184)  (live steps 2-3)
    short* h_all = (short*)(ws + 41943040);
    // qkv/ctx [50397184, 84213760)  (live steps 3-5)
    short* qb   = (short*)(ws + 50397184);
    short* kb   = qb + 4227072;
    short* vb   = kb + 4227072;
    short* ctxb = vb + 4227072;               // [75759616, 84213760)
    // Pwo [41943040, 75759616) over dead h_all/q/k/v  (live steps 5-6)
    float* Pwo = (float*)(ws + 41943040);
    // x1 [84213760, 101122048)  (live steps 6-9b)
    float* x1 = (float*)(ws + 84213760);
    // h2_reg [0, 8388608) over dead wq..wo            (live steps 6-7)
    short* h2_reg = (short*)ws;
    // h2_sum [75759616, 75825152) over dead ctx       (live steps 6-7b)
    short* h2_sum = (short*)(ws + 75759616);
    // f1_reg [41943040, 75497472) over dead Pwo       (live steps 7-9; ends BEFORE h2_sum)
    short* f1_reg = (short*)(ws + 41943040);
    // f1_sum [75825152, 76087296) over dead ctx       (live steps 7b-8)
    short* f1_sum = (short*)(ws + 75825152);
    // Psum [8388608, 10485760) over dead f1s_b        (live steps 8-8b)
    float* Psum = (float*)(ws + 8388608);
    // Pf2 [0, 33554432) over dead wts/h2_reg/Psum     (live steps 9-9b)
    float* Pf2 = (float*)ws;

    // 1. weights -> bf16
    cvt_w<<<20480, 256, 0, stream>>>(wq, wk, wv, wo, sf1w, sf2w, rf1w, rf2w, wbf);
    // 2. pre-attn LN
    ln_k<0><<<4128, 256, 0, stream>>>(x, nullptr, nullptr, lsg, lsb, lrg, lrb,
                                      h_all, nullptr, nullptr);
    // 3. fused QKV
    gemm_bt<0><<<dim3(33, 24, 1), 256, 0, stream>>>(h_all, 4128, 1024, 1024,
        wq_b, wk_b, wv_b, nullptr, qb, kb, vb, 0);
    // 4. attention
    attn_reg<<<dim3(16, 16, 2), 256, 0, stream>>>(qb, kb, vb, ctxb);
    attn_sum<<<512, 64, 0, stream>>>(qb, kb, vb, ctxb);
    // 5. W_O split-K=2 -> Pwo
    gemm_bt<1><<<dim3(33, 8, 2), 256, 0, stream>>>(ctxb, 4128, 1024, 512,
        wo_b, nullptr, nullptr, nullptr, Pwo, nullptr, nullptr, 4227072);
    // 6. fused WO-reduce + pre-FFN LN: x1 = x + P0 + P1; scatter LN(x1)
    //    (h2_reg/h2_sum/x1 all disjoint from Pwo)
    ln_k<1><<<4128, 256, 0, stream>>>(x, Pwo, x1, fsg, fsb, frg, frb,
                                      nullptr, h2_sum, h2_reg);
    // 7. FFN1-reg (f1_reg over dead Pwo; clear of h2_sum)
    gemm_bt<2><<<dim3(32, 32, 1), 256, 0, stream>>>(h2_reg, 4096, 1024, 1024,
        f1r_b, nullptr, nullptr, rf1b, f1_reg, nullptr, nullptr, 0);
    // 7b. FFN1-sum
    gemm_bt<2><<<dim3(1, 32, 1), 256, 0, stream>>>(h2_sum, 32, 1024, 1024,
        f1s_b, nullptr, nullptr, sf1b, f1_sum, nullptr, nullptr, 0);
    // 8. FFN2-sum split-K=16 -> Psum (over dead f1s_b), reduce -> out (sum rows)
    gemm_bt<1><<<dim3(1, 8, 16), 256, 0, stream>>>(f1_sum, 32, 4096, 256,
        f2s_b, nullptr, nullptr, nullptr, Psum, nullptr, nullptr, 32768);
    reduce_f2sum<<<32, 256, 0, stream>>>(x1, Psum, sf2b, out);
    // 9. FFN2-reg split-K=2 -> Pf2, reduce -> out (reg rows)
    gemm_bt<1><<<dim3(32, 8, 2), 256, 0, stream>>>(f1_reg, 4096, 4096, 2048,
        f2r_b, nullptr, nullptr, nullptr, Pf2, nullptr, nullptr, 4194304);
    reduce_f2reg<<<4096, 256, 0, stream>>>(x1, Pf2, rf2b, out);
}